// Round 13
// baseline (1010.371 us; speedup 1.0000x reference)
//
#include <hip/hip_runtime.h>
#include <hip/hip_bf16.h>
#include <stdint.h>

// Problem constants
#define Bq 8
#define Lq 2048
#define Dq 1024
#define Pq 4
#define Kq 4096          // D*P
#define LPAD 2056        // 3 zero rows + 2048 data + 5 slack, per batch
// GEMM tiling: 256x256, BK=64, 8 waves, SKEWED WAVE-GROUP pipeline,
// SCALAR role branch (readfirstlane) -> no exec-mask phi copies.
#define BM 256
#define BN 256
#define BK 64

typedef __attribute__((ext_vector_type(8))) short short8;   // 8 bf16 (4 VGPRs)
typedef __attribute__((ext_vector_type(4))) float f32x4;

__device__ __forceinline__ unsigned short f2bf(float f) {
  unsigned u = __float_as_uint(f);
  u += 0x7FFFu + ((u >> 16) & 1u);   // round-to-nearest-even
  return (unsigned short)(u >> 16);
}

__device__ __forceinline__ void gload_lds16(const void* g, void* l) {
  __builtin_amdgcn_global_load_lds(
      (const __attribute__((address_space(1))) void*)g,
      (__attribute__((address_space(3))) void*)l, 16, 0, 0);
}

// ---- merged prep: blocks [0,8224) do xp, blocks [8224,10272) do Wp ----
__global__ void k_prep(const float* __restrict__ x, const float* __restrict__ W,
                       unsigned short* __restrict__ xp, unsigned short* __restrict__ Wp) {
  if (blockIdx.x < 8224u) {
    unsigned g = blockIdx.x * blockDim.x + threadIdx.x;
    unsigned base = g * 8;
    const unsigned total = (unsigned)Bq * LPAD * Dq;
    if (base >= total) return;
    unsigned t = base >> 10;            // b*LPAD + r
    unsigned b = t / LPAD;
    unsigned r = t - b * LPAD;
    unsigned d = base & 1023;
    short8 o;
    if (r >= 3 && r < 3 + Lq) {
      const float* s = x + ((size_t)b * Lq + (r - 3)) * Dq + d;
      float4 v0 = *(const float4*)(s);
      float4 v1 = *(const float4*)(s + 4);
      o[0] = (short)f2bf(v0.x); o[1] = (short)f2bf(v0.y);
      o[2] = (short)f2bf(v0.z); o[3] = (short)f2bf(v0.w);
      o[4] = (short)f2bf(v1.x); o[5] = (short)f2bf(v1.y);
      o[6] = (short)f2bf(v1.z); o[7] = (short)f2bf(v1.w);
    } else {
      o = (short8)0;
    }
    *(short8*)(xp + base) = o;
  } else {
    unsigned g = (blockIdx.x - 8224u) * blockDim.x + threadIdx.x;
    unsigned base = g * 8;
    unsigned d = base >> 12;
    unsigned rem = base & 4095;
    unsigned dp = rem >> 2;                               // even
    const float4* src = (const float4*)(W + base);
    float4 v0 = src[0];
    float4 v1 = src[1];
    float a0[4] = {v0.x, v0.y, v0.z, v0.w};
    float a1[4] = {v1.x, v1.y, v1.z, v1.w};
#pragma unroll
    for (int i = 0; i < 4; ++i) {
      unsigned packed = (unsigned)f2bf(a0[i]) | ((unsigned)f2bf(a1[i]) << 16);
      *(unsigned*)(Wp + (size_t)d * 4096 + (size_t)i * 1024 + dp) = packed;
    }
  }
}

// ====== 256x256 GEMM, skewed wave-group pipeline (scalar role branch) ======
// C[m][n] = sum_k A[m][k]*Wp[n][k] + bias[n],  A[m][i*1024+d'] = xp[b][l+3-i][d']
// LDS (128 KiB): A in [0,64K): [buf:32K][h:16K]; B in [64K,128K): same.
//   byte within 128B row: SWIZZLED  phys_c = log_c ^ ((r&7)<<4)
// Waves 0-3 = group E (wm=0, rows 0..127), waves 4-7 = O (wm=1); 1 E + 1 O
// wave per SIMD. Roles alternate per phase: {read tile k} vs {MFMA tile k-1};
// MFMA pipe and LDS read unit busy concurrently on every SIMD.
// gEs is readfirstlane'd -> scalar branch, no exec-mask phis on the 96 frag
// regs (R12's spill source). Hazard/vmcnt ledger identical to R12 (verified):
// stage V(buf0) in phE1 lands <= VM0 @ phO1-end, first read phE2; buf0's
// prior tile fully read 2 phases earlier; barriers separate all WAR pairs.

#define VM0 asm volatile("s_waitcnt vmcnt(0)" ::: "memory")
#define BAR __builtin_amdgcn_s_barrier()
#define SBF __builtin_amdgcn_sched_barrier(0xF)

#define STAGE_T(buf, kt) do { \
    if (gEs) { \
      _Pragma("unroll") for (int h_ = 0; h_ < 2; ++h_) \
      _Pragma("unroll") for (int q_ = 0; q_ < 4; ++q_) { \
        const unsigned scl_ = (((unsigned)(bRow0 + ((q_ >> 1) * 128 + (q_ & 1) * 32 + h_ * 64) - ((kt) >> 4))) << 11) + (((unsigned)(kt) & 15u) << 7); \
        gload_lds16((const char*)xp + (thrS + scl_), \
                    lds + (((buf) << 15) + (h_ << 14) + (q_ << 12)) + (tt << 4)); \
      } \
    } else { \
      _Pragma("unroll") for (int h_ = 0; h_ < 2; ++h_) \
      _Pragma("unroll") for (int q_ = 0; q_ < 4; ++q_) { \
        const unsigned scl_ = (((unsigned)(n0 + q_ * 64 + h_ * 32)) << 13) + ((unsigned)(kt) << 7); \
        gload_lds16((const char*)Wp + (thrS + scl_), \
                    lds + 65536 + (((buf) << 15) + (h_ << 14) + (q_ << 12)) + (tt << 4)); \
      } \
    } \
  } while (0)

#define RD_A(dst, buf, h) do { \
    _Pragma("unroll") for (int mi = 0; mi < 4; ++mi) \
    _Pragma("unroll") for (int kk = 0; kk < 2; ++kk) \
      dst[mi][kk] = *(const short8*)(lds + aK[kk] + (((buf) << 15) + ((h) << 14) + (mi << 11))); \
  } while (0)

#define RD_B(dst, buf, h) do { \
    _Pragma("unroll") for (int ni = 0; ni < 2; ++ni) \
    _Pragma("unroll") for (int kk = 0; kk < 2; ++kk) \
      dst[ni][kk] = *(const short8*)(lds + bK[kk] + (((buf) << 15) + ((h) << 14) + (ni << 11))); \
  } while (0)

#define READ_TILE(buf) do { \
    RD_A(fa0, buf, 0); RD_A(fa1, buf, 1); RD_B(bX, buf, 0); RD_B(bY, buf, 1); \
  } while (0)

#define MFMAH(mh, nh, A, Bv) do { \
    _Pragma("unroll") for (int kk = 0; kk < 2; ++kk) \
    _Pragma("unroll") for (int mi = 0; mi < 4; ++mi) \
    _Pragma("unroll") for (int ni = 0; ni < 2; ++ni) \
      acc[(mh) * 4 + mi][(nh) * 2 + ni] = __builtin_amdgcn_mfma_f32_16x16x32_bf16( \
          A[mi][kk], Bv[ni][kk], acc[(mh) * 4 + mi][(nh) * 2 + ni], 0, 0, 0); \
  } while (0)

#define MFMA_TILE() do { \
    __builtin_amdgcn_s_setprio(1); \
    MFMAH(0, 0, fa0, bX); MFMAH(0, 1, fa0, bY); \
    MFMAH(1, 0, fa1, bX); MFMAH(1, 1, fa1, bY); \
    __builtin_amdgcn_s_setprio(0); \
  } while (0)

__global__ void __launch_bounds__(512, 1)
k_gemm(const unsigned short* __restrict__ xp,
       const unsigned short* __restrict__ Wp,
       const float* __restrict__ bias,
       float* __restrict__ out) {
  __shared__ __attribute__((aligned(16))) unsigned char lds[131072];

  const int tid  = threadIdx.x;
  const int lane = tid & 63;
  const int w    = tid >> 6;       // 0..7
  const int wm   = w >> 2;         // 0 = group E, 1 = group O
  const int wn   = w & 3;          // 0..3
  // SCALAR role flag: readfirstlane -> SGPR -> s_cbranch (no exec-mask phis)
  const int gEs  = (__builtin_amdgcn_readfirstlane(wm) == 0);

  // bijective XCD swizzle (256 blocks): each XCD gets a contiguous
  // 8-mtile x 4-ntile chunk -> A fetched once per XCD.
  const int bid = blockIdx.x;
  const int swz = (bid & 7) * 32 + (bid >> 3);
  const int m0 = (swz >> 2) * BM;
  const int n0 = (swz & 3) * BN;
  const int b  = m0 >> 11;
  const int l0 = m0 & 2047;
  const int bRow0 = b * LPAD + l0 + 3;           // SGPR (wave-uniform)

  // ---- staging per-thread invariant ----
  const int tt = tid & 255;                      // 0..255 within group
  const int sr = tt >> 3;                        // 0..31
  const unsigned clogB = ((unsigned)((tid & 7) ^ (sr & 7))) << 4;   // swizzled col bytes
  const unsigned thrS = gEs ? ((((unsigned)sr) << 11) + clogB)      // A: row*2048 B
                            : ((((unsigned)sr) << 13) + clogB);     // B: row*8192 B

  // ---- ds_read base addresses (4 VGPRs; buf/h/mi/ni via offset immediates) ----
  unsigned aK[2], bK[2];
  {
    const int slot = (lane >> 4) << 4;
    const int sw = (lane & 7) << 4;
#pragma unroll
    for (int kk = 0; kk < 2; ++kk) {
      const int cb = (kk * 64 + slot) ^ sw;
      aK[kk] = (unsigned)((wm << 13) + ((lane & 15) << 7) + cb);
      bK[kk] = (unsigned)(65536 + ((wn * 32 + (lane & 15)) << 7) + cb);
    }
  }

  f32x4 acc[8][4] = {};
  short8 fa0[4][2], fa1[4][2], bX[2][2], bY[2][2];

  // ---- prologue: stage tile0; ph0: E reads t0, both stage t1; ph1 ----
  STAGE_T(0, 0);                     // E: A(t0), O: B(t0)
  VM0; BAR; SBF;
  if (gEs) { READ_TILE(0); }         // ph0: E reads t0; O idle
  STAGE_T(1, 1);
  BAR; SBF;
  if (gEs) { MFMA_TILE(); } else { READ_TILE(0); }   // ph1
  VM0; BAR; SBF;

  // ---- main loop: 31 iters; tiles U=2it+1 (buf1), V=2it+2 (buf0) ----
#pragma unroll 1
  for (int it = 0; it < 31; ++it) {
    const int V = 2 * it + 2;
    // phE1: E read U(buf1); O MFMA T=2it; stage V(buf0)
    STAGE_T(0, V);
    if (gEs) { READ_TILE(1); } else { MFMA_TILE(); }
    BAR; SBF;
    // phO1: E MFMA U; O read U(buf1)
    if (gEs) { MFMA_TILE(); } else { READ_TILE(1); }
    VM0; BAR; SBF;
    // phE2: E read V(buf0); O MFMA U; stage V+1(buf1)
    STAGE_T(1, V + 1);
    if (gEs) { READ_TILE(0); } else { MFMA_TILE(); }
    BAR; SBF;
    // phO2: E MFMA V; O read V(buf0)
    if (gEs) { MFMA_TILE(); } else { READ_TILE(0); }
    VM0; BAR; SBF;
  }

  // ---- epilogue: tile 63 (buf1) ----
  if (gEs) { READ_TILE(1); } else { MFMA_TILE(); }   // E rd t63; O MFMA t62
  BAR; SBF;
  if (gEs) { MFMA_TILE(); } else { READ_TILE(1); }   // E MFMA t63; O rd t63
  BAR; SBF;
  if (!gEs) { MFMA_TILE(); }                          // O MFMA t63

  // ---- C write: col = lane&15, row = (lane>>4)*4 + reg ----
#pragma unroll
  for (int nig = 0; nig < 4; ++nig) {
    const int col = n0 + wn * 64 + nig * 16 + (lane & 15);
    const float bv = bias[col];
#pragma unroll
    for (int mig = 0; mig < 8; ++mig) {
      const int row0 = m0 + wm * 128 + mig * 16 + ((lane >> 4) << 2);
#pragma unroll
      for (int t2 = 0; t2 < 4; ++t2)
        out[(size_t)(row0 + t2) * Dq + col] = acc[mig][nig][t2] + bv;
    }
  }
}

// ---- slow-but-correct fallback if workspace is too small ----
__global__ void k_naive(const float* __restrict__ x, const float* __restrict__ W,
                        const float* __restrict__ bias, float* __restrict__ out) {
  size_t g = (size_t)blockIdx.x * blockDim.x + threadIdx.x;
  const size_t total = (size_t)Bq * Lq * Dq;
  if (g >= total) return;
  int d = (int)(g & 1023);
  int l = (int)((g >> 10) & 2047);
  int b = (int)(g >> 21);
  float s = bias[d];
  for (int i = 0; i < Pq; ++i) {
    if (l - i < 0) continue;
    const float* xr = x + ((size_t)b * Lq + (l - i)) * Dq;
    const float* wr = W + (size_t)d * Kq + i;
    float accv = 0.f;
    for (int dp = 0; dp < Dq; ++dp) accv += xr[dp] * wr[(size_t)dp * 4];
    s += accv;
  }
  out[g] = s;
}

extern "C" void kernel_launch(void* const* d_in, const int* in_sizes, int n_in,
                              void* d_out, int out_size, void* d_ws, size_t ws_size,
                              hipStream_t stream) {
  const float* x    = (const float*)d_in[0];
  const float* W    = (const float*)d_in[1];
  const float* bias = (const float*)d_in[2];
  float* out = (float*)d_out;

  const size_t WP_BYTES = (size_t)Dq * Kq * sizeof(unsigned short);        // 8 MiB
  const size_t XP_BYTES = (size_t)Bq * LPAD * Dq * sizeof(unsigned short); // ~33.7 MB

  if (ws_size < WP_BYTES + XP_BYTES) {
    const size_t total = (size_t)Bq * Lq * Dq;
    k_naive<<<(unsigned)((total + 255) / 256), 256, 0, stream>>>(x, W, bias, out);
    return;
  }

  unsigned short* Wp = (unsigned short*)d_ws;
  unsigned short* xp = (unsigned short*)((char*)d_ws + WP_BYTES);

  k_prep<<<10272, 256, 0, stream>>>(x, W, xp, Wp);
  k_gemm<<<dim3((Bq * Lq / BM) * (Dq / BN)), 512, 0, stream>>>(xp, Wp, bias, out);
}

// Round 14
// 155.938 us; speedup vs baseline: 6.4793x; 6.4793x over previous
//
#include <hip/hip_runtime.h>
#include <hip/hip_bf16.h>
#include <stdint.h>

// Problem constants
#define Bq 8
#define Lq 2048
#define Dq 1024
#define Pq 4
#define Kq 4096          // D*P
#define LPAD 2056        // 3 zero rows + 2048 data + 5 slack, per batch
// GEMM tiling: 256x256, BK=64, FOUR waves (1/SIMD, 512-reg budget),
// per-wave 128x128 output -> per-CU LDS read traffic 1.5x lower than 8-wave.
// 2 kk-sub-phases per K-tile; all ds_reads one sub-phase ahead of their MFMA.
#define BM 256
#define BN 256
#define BK 64

typedef __attribute__((ext_vector_type(8))) short short8;   // 8 bf16 (4 VGPRs)
typedef __attribute__((ext_vector_type(4))) float f32x4;

__device__ __forceinline__ unsigned short f2bf(float f) {
  unsigned u = __float_as_uint(f);
  u += 0x7FFFu + ((u >> 16) & 1u);   // round-to-nearest-even
  return (unsigned short)(u >> 16);
}

__device__ __forceinline__ void gload_lds16(const void* g, void* l) {
  __builtin_amdgcn_global_load_lds(
      (const __attribute__((address_space(1))) void*)g,
      (__attribute__((address_space(3))) void*)l, 16, 0, 0);
}

// ---- merged prep: blocks [0,8224) do xp, blocks [8224,10272) do Wp ----
__global__ void k_prep(const float* __restrict__ x, const float* __restrict__ W,
                       unsigned short* __restrict__ xp, unsigned short* __restrict__ Wp) {
  if (blockIdx.x < 8224u) {
    unsigned g = blockIdx.x * blockDim.x + threadIdx.x;
    unsigned base = g * 8;
    const unsigned total = (unsigned)Bq * LPAD * Dq;
    if (base >= total) return;
    unsigned t = base >> 10;            // b*LPAD + r
    unsigned b = t / LPAD;
    unsigned r = t - b * LPAD;
    unsigned d = base & 1023;
    short8 o;
    if (r >= 3 && r < 3 + Lq) {
      const float* s = x + ((size_t)b * Lq + (r - 3)) * Dq + d;
      float4 v0 = *(const float4*)(s);
      float4 v1 = *(const float4*)(s + 4);
      o[0] = (short)f2bf(v0.x); o[1] = (short)f2bf(v0.y);
      o[2] = (short)f2bf(v0.z); o[3] = (short)f2bf(v0.w);
      o[4] = (short)f2bf(v1.x); o[5] = (short)f2bf(v1.y);
      o[6] = (short)f2bf(v1.z); o[7] = (short)f2bf(v1.w);
    } else {
      o = (short8)0;
    }
    *(short8*)(xp + base) = o;
  } else {
    unsigned g = (blockIdx.x - 8224u) * blockDim.x + threadIdx.x;
    unsigned base = g * 8;
    unsigned d = base >> 12;
    unsigned rem = base & 4095;
    unsigned dp = rem >> 2;                               // even
    const float4* src = (const float4*)(W + base);
    float4 v0 = src[0];
    float4 v1 = src[1];
    float a0[4] = {v0.x, v0.y, v0.z, v0.w};
    float a1[4] = {v1.x, v1.y, v1.z, v1.w};
#pragma unroll
    for (int i = 0; i < 4; ++i) {
      unsigned packed = (unsigned)f2bf(a0[i]) | ((unsigned)f2bf(a1[i]) << 16);
      *(unsigned*)(Wp + (size_t)d * 4096 + (size_t)i * 1024 + dp) = packed;
    }
  }
}

// ====== 256x256 GEMM, 4 fat waves, kk-sub-phase read-ahead ======
// C[m][n] = sum_k A[m][k]*Wp[n][k] + bias[n],  A[m][i*1024+d'] = xp[b][l+3-i][d']
// LDS (128 KiB): A tiles [0,64K): buf*32K, row r (0..255) at r*128B;
//                B tiles [64K,128K): same. Swizzle phys_c = log_c ^ ((r&7)<<4).
// 4 waves: wm=w>>1 (rows wm*128..), wn=w&1 (cols wn*128..). 1 wave/SIMD ->
// 512-reg budget: acc 256 + two frag sets (2x64) + addr ~15 = ~410.
// Per K-tile t (buf p=t&1), 2 sub-phases:
//  alpha(t): rd set1 <- kk=1 of t (16 ds);  MFMA set0 (64, kk=0);        BAR
//  beta(t):  stage t+2 -> buf p (16 gloads); VM16 (drains t+1's stages);
//            BAR; rd set0 <- kk=0 of t+1 (buf p^1); MFMA set1 (64, kk=1)
// Every ds_read is consumed exactly one sub-phase later (no lgkm stall);
// every stage is issued ~1.5 tiles (~2500 cyc) before its first read (HBM
// latency hidden); alpha-end BAR separates t's kk1 reads from beta's stage
// into the same buffer; beta's VM16+BAR publishes t+1 before its reads.

#define VM16 asm volatile("s_waitcnt vmcnt(16)" ::: "memory")
#define VM0  asm volatile("s_waitcnt vmcnt(0)"  ::: "memory")
#define BAR  __builtin_amdgcn_s_barrier()

// wave w stages A rows [64w,64w+64) and B rows [64w,64w+64): 8+8 gloads of
// 8 rows each (64 lanes x 16B = 1KB = 8 rows x 128B).
#define STAGE(buf, kt) do { \
    const unsigned sclA_ = (((unsigned)(bRow0 - ((kt) >> 4))) << 11) + (((unsigned)(kt) & 15u) << 7); \
    const unsigned sclB_ = nScl + ((unsigned)(kt) << 7); \
    _Pragma("unroll") for (int j_ = 0; j_ < 8; ++j_) \
      gload_lds16((const char*)xp + (thrA + (unsigned)(j_ * 16384) + sclA_), \
                  lds + ((buf) << 15) + (wBase + (j_ << 10))); \
    _Pragma("unroll") for (int j_ = 0; j_ < 8; ++j_) \
      gload_lds16((const char*)Wp + (thrB + (unsigned)(j_ * 65536) + sclB_), \
                  lds + 65536 + ((buf) << 15) + (wBase + (j_ << 10))); \
  } while (0)

#define RD_SET(SA, SB, buf, kk) do { \
    _Pragma("unroll") for (int mi_ = 0; mi_ < 8; ++mi_) \
      SA[mi_] = *(const short8*)(lds + ((buf) << 15) + (mi_ << 11) + aK[kk]); \
    _Pragma("unroll") for (int ni_ = 0; ni_ < 8; ++ni_) \
      SB[ni_] = *(const short8*)(lds + ((buf) << 15) + (ni_ << 11) + bK[kk]); \
  } while (0)

#define MFMA_SET(SA, SB) do { \
    __builtin_amdgcn_s_setprio(1); \
    _Pragma("unroll") for (int mi_ = 0; mi_ < 8; ++mi_) \
    _Pragma("unroll") for (int ni_ = 0; ni_ < 8; ++ni_) \
      acc[mi_][ni_] = __builtin_amdgcn_mfma_f32_16x16x32_bf16( \
          SA[mi_], SB[ni_], acc[mi_][ni_], 0, 0, 0); \
    __builtin_amdgcn_s_setprio(0); \
  } while (0)

__global__ void __launch_bounds__(256, 1)
k_gemm(const unsigned short* __restrict__ xp,
       const unsigned short* __restrict__ Wp,
       const float* __restrict__ bias,
       float* __restrict__ out) {
  __shared__ __attribute__((aligned(16))) unsigned char lds[131072];

  const int tid  = threadIdx.x;
  const int lane = tid & 63;
  const int w    = tid >> 6;       // 0..3
  const int wm   = w >> 1;         // 0..1
  const int wn   = w & 1;          // 0..1

  // bijective XCD swizzle (256 blocks): each XCD gets a contiguous
  // 8-mtile x 4-ntile chunk -> A fetched once per XCD.
  const int bid = blockIdx.x;
  const int swz = (bid & 7) * 32 + (bid >> 3);
  const int m0 = (swz >> 2) * BM;
  const int n0 = (swz & 3) * BN;
  const int b  = m0 >> 11;
  const int l0 = m0 & 2047;
  const int bRow0 = b * LPAD + l0 + 3;           // SGPR (wave-uniform)
  const unsigned nScl = (unsigned)n0 << 13;      // n0 * 8192 bytes

  // ---- staging per-thread invariants ----
  // row-in-tile = 64w + 8j + (lane>>3); chunk = (lane&7) ^ ((lane>>3)&7)
  const unsigned rowT = (unsigned)(64 * w + ((tid >> 3) & 7));
  const unsigned chnk = ((unsigned)((tid & 7) ^ ((tid >> 3) & 7))) << 4;
  const unsigned thrA = (rowT << 11) + chnk;     // row*2048 + chunk*16
  const unsigned thrB = (rowT << 13) + chnk;     // row*8192 + chunk*16
  const unsigned wBase = ((unsigned)w << 13) + ((unsigned)lane << 4);

  // ---- ds_read base addresses (4 VGPRs; buf/mi/ni via offset immediates) ----
  unsigned aK[2], bK[2];
  {
#pragma unroll
    for (int kk = 0; kk < 2; ++kk) {
      const int cb = (kk * 64 + ((lane >> 4) << 4)) ^ ((lane & 7) << 4);
      aK[kk] = (unsigned)(((wm * 128 + (lane & 15)) << 7) + cb);
      bK[kk] = (unsigned)(65536 + ((wn * 128 + (lane & 15)) << 7) + cb);
    }
  }

  f32x4 acc[8][8] = {};
  short8 s0a[8], s0b[8], s1a[8], s1b[8];

  // ---- prologue: stage tiles 0,1; read kk0 of tile 0 ----
  STAGE(0, 0);
  STAGE(1, 1);
  VM16;                              // tile0 stages drained (own wave)
  BAR;                               // all waves' tile0 visible
  RD_SET(s0a, s0b, 0, 0);

  // ---- main loop: 31 iters, tiles T=2it (buf0), U=T+1 (buf1) ----
#pragma unroll 1
  for (int it = 0; it < 31; ++it) {
    const int T = it * 2;
    // alpha(T)
    RD_SET(s1a, s1b, 0, 1);
    MFMA_SET(s0a, s0b);
    BAR;
    // beta(T)
    STAGE(0, T + 2);
    VM16; BAR;                       // publish tile U
    RD_SET(s0a, s0b, 1, 0);
    MFMA_SET(s1a, s1b);
    // alpha(U)
    RD_SET(s1a, s1b, 1, 1);
    MFMA_SET(s0a, s0b);
    BAR;
    // beta(U)
    STAGE(1, T + 3);
    VM16; BAR;                       // publish tile T+2
    RD_SET(s0a, s0b, 0, 0);
    MFMA_SET(s1a, s1b);
  }

  // ---- epilogue: tiles 62 (buf0), 63 (buf1); both staged in-loop ----
  // alpha(62)
  RD_SET(s1a, s1b, 0, 1);
  MFMA_SET(s0a, s0b);
  BAR;
  // beta(62): no stage
  VM0; BAR;                          // publish tile 63
  RD_SET(s0a, s0b, 1, 0);
  MFMA_SET(s1a, s1b);
  // alpha(63)
  RD_SET(s1a, s1b, 1, 1);
  MFMA_SET(s0a, s0b);
  // beta(63)
  MFMA_SET(s1a, s1b);

  // ---- C write: col = lane&15, row = (lane>>4)*4 + reg ----
#pragma unroll
  for (int ni = 0; ni < 8; ++ni) {
    const int col = n0 + wn * 128 + ni * 16 + (lane & 15);
    const float bv = bias[col];
#pragma unroll
    for (int mi = 0; mi < 8; ++mi) {
      const int row0 = m0 + wm * 128 + mi * 16 + ((lane >> 4) << 2);
#pragma unroll
      for (int t2 = 0; t2 < 4; ++t2)
        out[(size_t)(row0 + t2) * Dq + col] = acc[mi][ni][t2] + bv;
    }
  }
}

// ---- slow-but-correct fallback if workspace is too small ----
__global__ void k_naive(const float* __restrict__ x, const float* __restrict__ W,
                        const float* __restrict__ bias, float* __restrict__ out) {
  size_t g = (size_t)blockIdx.x * blockDim.x + threadIdx.x;
  const size_t total = (size_t)Bq * Lq * Dq;
  if (g >= total) return;
  int d = (int)(g & 1023);
  int l = (int)((g >> 10) & 2047);
  int b = (int)(g >> 21);
  float s = bias[d];
  for (int i = 0; i < Pq; ++i) {
    if (l - i < 0) continue;
    const float* xr = x + ((size_t)b * Lq + (l - i)) * Dq;
    const float* wr = W + (size_t)d * Kq + i;
    float accv = 0.f;
    for (int dp = 0; dp < Dq; ++dp) accv += xr[dp] * wr[(size_t)dp * 4];
    s += accv;
  }
  out[g] = s;
}

extern "C" void kernel_launch(void* const* d_in, const int* in_sizes, int n_in,
                              void* d_out, int out_size, void* d_ws, size_t ws_size,
                              hipStream_t stream) {
  const float* x    = (const float*)d_in[0];
  const float* W    = (const float*)d_in[1];
  const float* bias = (const float*)d_in[2];
  float* out = (float*)d_out;

  const size_t WP_BYTES = (size_t)Dq * Kq * sizeof(unsigned short);        // 8 MiB
  const size_t XP_BYTES = (size_t)Bq * LPAD * Dq * sizeof(unsigned short); // ~33.7 MB

  if (ws_size < WP_BYTES + XP_BYTES) {
    const size_t total = (size_t)Bq * Lq * Dq;
    k_naive<<<(unsigned)((total + 255) / 256), 256, 0, stream>>>(x, W, bias, out);
    return;
  }

  unsigned short* Wp = (unsigned short*)d_ws;
  unsigned short* xp = (unsigned short*)((char*)d_ws + WP_BYTES);

  k_prep<<<10272, 256, 0, stream>>>(x, W, xp, Wp);
  k_gemm<<<dim3((Bq * Lq / BM) * (Dq / BN)), 256, 0, stream>>>(xp, Wp, bias, out);
}

// Round 15
// 152.034 us; speedup vs baseline: 6.6457x; 1.0257x over previous
//
#include <hip/hip_runtime.h>
#include <hip/hip_bf16.h>
#include <stdint.h>

// Problem constants
#define Bq 8
#define Lq 2048
#define Dq 1024
#define Pq 4
#define Kq 4096          // D*P
#define LPAD 2056        // 3 zero rows + 2048 data + 5 slack, per batch
// GEMM tiling: 256x128, BK=32, 512 blocks (2/CU -> cross-block TLP),
// 4 waves/block each 128x64 out, 3-buffer LDS rotation, counted vmcnt(6).
#define BM 256
#define BN 128
#define BK 32

typedef __attribute__((ext_vector_type(8))) short short8;   // 8 bf16 (4 VGPRs)
typedef __attribute__((ext_vector_type(4))) float f32x4;

__device__ __forceinline__ unsigned short f2bf(float f) {
  unsigned u = __float_as_uint(f);
  u += 0x7FFFu + ((u >> 16) & 1u);   // round-to-nearest-even
  return (unsigned short)(u >> 16);
}

__device__ __forceinline__ void gload_lds16(const void* g, void* l) {
  __builtin_amdgcn_global_load_lds(
      (const __attribute__((address_space(1))) void*)g,
      (__attribute__((address_space(3))) void*)l, 16, 0, 0);
}

// ---- merged prep: blocks [0,8224) do xp, blocks [8224,10272) do Wp ----
__global__ void k_prep(const float* __restrict__ x, const float* __restrict__ W,
                       unsigned short* __restrict__ xp, unsigned short* __restrict__ Wp) {
  if (blockIdx.x < 8224u) {
    unsigned g = blockIdx.x * blockDim.x + threadIdx.x;
    unsigned base = g * 8;
    const unsigned total = (unsigned)Bq * LPAD * Dq;
    if (base >= total) return;
    unsigned t = base >> 10;            // b*LPAD + r
    unsigned b = t / LPAD;
    unsigned r = t - b * LPAD;
    unsigned d = base & 1023;
    short8 o;
    if (r >= 3 && r < 3 + Lq) {
      const float* s = x + ((size_t)b * Lq + (r - 3)) * Dq + d;
      float4 v0 = *(const float4*)(s);
      float4 v1 = *(const float4*)(s + 4);
      o[0] = (short)f2bf(v0.x); o[1] = (short)f2bf(v0.y);
      o[2] = (short)f2bf(v0.z); o[3] = (short)f2bf(v0.w);
      o[4] = (short)f2bf(v1.x); o[5] = (short)f2bf(v1.y);
      o[6] = (short)f2bf(v1.z); o[7] = (short)f2bf(v1.w);
    } else {
      o = (short8)0;
    }
    *(short8*)(xp + base) = o;
  } else {
    unsigned g = (blockIdx.x - 8224u) * blockDim.x + threadIdx.x;
    unsigned base = g * 8;
    unsigned d = base >> 12;
    unsigned rem = base & 4095;
    unsigned dp = rem >> 2;                               // even
    const float4* src = (const float4*)(W + base);
    float4 v0 = src[0];
    float4 v1 = src[1];
    float a0[4] = {v0.x, v0.y, v0.z, v0.w};
    float a1[4] = {v1.x, v1.y, v1.z, v1.w};
#pragma unroll
    for (int i = 0; i < 4; ++i) {
      unsigned packed = (unsigned)f2bf(a0[i]) | ((unsigned)f2bf(a1[i]) << 16);
      *(unsigned*)(Wp + (size_t)d * 4096 + (size_t)i * 1024 + dp) = packed;
    }
  }
}

// ====== 256x128 GEMM, 2 blocks/CU, 3-buf rotation, counted vmcnt ======
// C[m][n] = sum_k A[m][k]*Wp[n][k] + bias[n],  A[m][i*1024+d'] = xp[b][l+3-i][d']
// LDS 72 KiB/block (2 resident/CU): B bufs at {0,8192,16384} (128 rows x 64B),
// A bufs at {24576,40960,57344} (256 rows x 64B).
//   row r: 4 16B-chunks; phys chunk = logical ^ ((r>>1)&3)  -> 8 lanes per
//   16B bank-group on reads = conflict-free floor.
// 4 waves: wm=w>>1 (rows wm*128..), wn=w&1 (cols wn*64..), per-wave 128x64.
// One phase per K-tile P (buf P%3):
//   [12 ds_reads tile P][6 gloads tile P+2 -> buf (P+2)%3][32 MFMA][VM6][BAR]
// Hazards: buf (P+2)%3 holds tile P-1, last read phase P-1 (barrier-sep);
// tile P+2 staged 2 phases (~2400cyc > 900 HBM) before read; VM6 at each
// phase end drains exactly through tile P+1's stages. Cross-BLOCK TLP: the
// other resident block's waves fill this block's VM/BAR/lgkm stalls.

#define VM6 asm volatile("s_waitcnt vmcnt(6)" ::: "memory")
#define VM0 asm volatile("s_waitcnt vmcnt(0)" ::: "memory")
#define BAR __builtin_amdgcn_s_barrier()

#define STAGE_AB(AIMM, BIMM, kt) do { \
    const unsigned sclA_ = (((unsigned)(bRow0 - ((kt) >> 5))) << 11) + (((unsigned)(kt) & 31u) << 6); \
    const unsigned sclB_ = nScl + ((unsigned)(kt) << 6); \
    _Pragma("unroll") for (int j_ = 0; j_ < 4; ++j_) \
      gload_lds16((const char*)xp + (thrA + (unsigned)(j_ * 131072) + sclA_), \
                  lds + (AIMM) + (j_ << 12) + (tid << 4)); \
    _Pragma("unroll") for (int j_ = 0; j_ < 2; ++j_) \
      gload_lds16((const char*)Wp + (thrB + (unsigned)(j_ * 524288) + sclB_), \
                  lds + (BIMM) + (j_ << 12) + (tid << 4)); \
  } while (0)

#define READS(AIMM, BIMM) do { \
    _Pragma("unroll") for (int mi_ = 0; mi_ < 8; ++mi_) \
      fa[mi_] = *(const short8*)(lds + aVG[mi_] + (AIMM)); \
    _Pragma("unroll") for (int ni_ = 0; ni_ < 4; ++ni_) \
      fb[ni_] = *(const short8*)(lds + bVG[ni_] + (BIMM)); \
  } while (0)

#define MFMA32 do { \
    __builtin_amdgcn_s_setprio(1); \
    _Pragma("unroll") for (int mi_ = 0; mi_ < 8; ++mi_) \
    _Pragma("unroll") for (int ni_ = 0; ni_ < 4; ++ni_) \
      acc[mi_][ni_] = __builtin_amdgcn_mfma_f32_16x16x32_bf16( \
          fa[mi_], fb[ni_], acc[mi_][ni_], 0, 0, 0); \
    __builtin_amdgcn_s_setprio(0); \
  } while (0)

#define PHASE(AR, BR, AS, BS, kt) do { \
    READS(AR, BR); STAGE_AB(AS, BS, kt); MFMA32; VM6; BAR; \
  } while (0)

__global__ void __launch_bounds__(256, 2)
k_gemm(const unsigned short* __restrict__ xp,
       const unsigned short* __restrict__ Wp,
       const float* __restrict__ bias,
       float* __restrict__ out) {
  __shared__ __attribute__((aligned(16))) unsigned char lds[73728];

  const int tid  = threadIdx.x;
  const int lane = tid & 63;
  const int w    = tid >> 6;       // 0..3
  const int wm   = w >> 1;         // 0..1
  const int wn   = w & 1;          // 0..1

  // bijective XCD swizzle (512 blocks, 512%8==0): each XCD gets 8 m-tiles
  // x all 8 n-tiles -> A-panel reuse within the XCD's L2.
  const int bid = blockIdx.x;
  const int swz = (bid & 7) * 64 + (bid >> 3);
  const int m0 = (swz >> 3) * BM;
  const int n0 = (swz & 7) * BN;
  const int b  = m0 >> 11;
  const int l0 = m0 & 2047;
  const int bRow0 = b * LPAD + l0 + 3;           // SGPR (wave-uniform)
  const unsigned nScl = (unsigned)n0 << 13;      // n0 * 8192 B

  // ---- staging per-thread invariants ----
  // thread t: region row r=t>>2 (+64 per issue), phys chunk t&3,
  // logical chunk = (t&3) ^ ((t>>3)&3)   [= phys ^ swz(row), row-invariant mod 64]
  const unsigned rS   = (unsigned)(tid >> 2);
  const unsigned clS  = (unsigned)((tid & 3) ^ ((tid >> 3) & 3));
  const unsigned thrA = (rS << 11) + (clS << 4);   // A row stride 2048 B
  const unsigned thrB = (rS << 13) + (clS << 4);   // B row stride 8192 B

  // ---- ds_read addresses (12 VGPRs; buf via literal offset) ----
  const int r4 = lane & 15;
  const int chunk = ((lane >> 4) ^ ((r4 >> 1) & 3)) << 4;
  unsigned aVG[8], bVG[4];
#pragma unroll
  for (int mi = 0; mi < 8; ++mi)
    aVG[mi] = (unsigned)(((wm * 128 + mi * 16 + r4) << 6) + chunk);
#pragma unroll
  for (int ni = 0; ni < 4; ++ni)
    bVG[ni] = (unsigned)(((wn * 64 + ni * 16 + r4) << 6) + chunk);

  f32x4 acc[8][4] = {};
  short8 fa[8], fb[4];

  // ---- prologue: stage tiles 0 (buf0), 1 (buf1) ----
  STAGE_AB(24576, 0, 0);
  STAGE_AB(40960, 8192, 1);
  VM6;                               // tile0 drained (per-wave)
  BAR;

  // ---- main loop: 42 iters x 3 phases = tiles 0..125 ----
#pragma unroll 1
  for (int it = 0; it < 42; ++it) {
    const int k0 = it * 3;
    PHASE(24576, 0,     57344, 16384, k0 + 2);   // read buf0, stage buf2
    PHASE(40960, 8192,  24576, 0,     k0 + 3);   // read buf1, stage buf0
    PHASE(57344, 16384, 40960, 8192,  k0 + 4);   // read buf2, stage buf1
  }

  // ---- tail: tiles 126 (buf0), 127 (buf1) ----
  READS(24576, 0);
  MFMA32;
  VM0; BAR;                          // tile127 drained
  READS(40960, 8192);
  MFMA32;

  // ---- C write: col = lane&15, row = (lane>>4)*4 + reg ----
#pragma unroll
  for (int ni = 0; ni < 4; ++ni) {
    const int col = n0 + wn * 64 + ni * 16 + r4;
    const float bv = bias[col];
#pragma unroll
    for (int mi = 0; mi < 8; ++mi) {
      const int row0 = m0 + wm * 128 + mi * 16 + ((lane >> 4) << 2);
#pragma unroll
      for (int t2 = 0; t2 < 4; ++t2)
        out[(size_t)(row0 + t2) * Dq + col] = acc[mi][ni][t2] + bv;
    }
  }
}

// ---- slow-but-correct fallback if workspace is too small ----
__global__ void k_naive(const float* __restrict__ x, const float* __restrict__ W,
                        const float* __restrict__ bias, float* __restrict__ out) {
  size_t g = (size_t)blockIdx.x * blockDim.x + threadIdx.x;
  const size_t total = (size_t)Bq * Lq * Dq;
  if (g >= total) return;
  int d = (int)(g & 1023);
  int l = (int)((g >> 10) & 2047);
  int b = (int)(g >> 21);
  float s = bias[d];
  for (int i = 0; i < Pq; ++i) {
    if (l - i < 0) continue;
    const float* xr = x + ((size_t)b * Lq + (l - i)) * Dq;
    const float* wr = W + (size_t)d * Kq + i;
    float accv = 0.f;
    for (int dp = 0; dp < Dq; ++dp) accv += xr[dp] * wr[(size_t)dp * 4];
    s += accv;
  }
  out[g] = s;
}

extern "C" void kernel_launch(void* const* d_in, const int* in_sizes, int n_in,
                              void* d_out, int out_size, void* d_ws, size_t ws_size,
                              hipStream_t stream) {
  const float* x    = (const float*)d_in[0];
  const float* W    = (const float*)d_in[1];
  const float* bias = (const float*)d_in[2];
  float* out = (float*)d_out;

  const size_t WP_BYTES = (size_t)Dq * Kq * sizeof(unsigned short);        // 8 MiB
  const size_t XP_BYTES = (size_t)Bq * LPAD * Dq * sizeof(unsigned short); // ~33.7 MB

  if (ws_size < WP_BYTES + XP_BYTES) {
    const size_t total = (size_t)Bq * Lq * Dq;
    k_naive<<<(unsigned)((total + 255) / 256), 256, 0, stream>>>(x, W, bias, out);
    return;
  }

  unsigned short* Wp = (unsigned short*)d_ws;
  unsigned short* xp = (unsigned short*)((char*)d_ws + WP_BYTES);

  k_prep<<<10272, 256, 0, stream>>>(x, W, xp, Wp);
  k_gemm<<<dim3((Bq * Lq / BM) * (Dq / BN)), 256, 0, stream>>>(xp, Wp, bias, out);
}